// Round 7
// baseline (93.134 us; speedup 1.0000x reference)
//
#include <hip/hip_runtime.h>

#define NBOX 4000
#define NPAD 4096
#define BATCH 8
#define WPR 64          // 64-bit words per suppression row (padded stride)
#define MAXK 300

typedef unsigned long long u64;

// Static device scratch (deterministic across replays: everything consulted is
// rewritten every call; rows >= nvalid are never read).
// g_sup padded to NPAD rows so the NMS pipeline can stage block rows without
// any clamping (rows >= nv hold garbage but are never consulted).
__device__ u64 g_sup[BATCH][NPAD][WPR];           // ~16.8 MB full rows
__device__ u64 g_tile64[BATCH][64][64];           // word blk of row blk*64+r
__device__ float4 g_sorted[BATCH][NPAD];          // 512 KB
__device__ int g_nvalid[BATCH];

// ---------------------------------------------------------------------------
// Kernel 1: per-batch stable LSD radix sort (6 passes x 4 bits). (unchanged,
// proven bit-exact) Key k = 0x3F800000 - bits(fg): valid => fg > 0.5 => k in
// (0, 0x800000), fits 24 bits. Invalid/pad k = 0xFFFFFF sorts last. Stable
// blocked radix preserves original-index order for ties (jnp.argsort).
// ---------------------------------------------------------------------------
#define SORT_T 256
#define EPT 16
#define HP 264
#define KIDX(n) ((((n) >> 4) * 17) + ((n) & 15))
#define KSZ (256 * 17)

__global__ __launch_bounds__(SORT_T) void sort_kernel(const float* __restrict__ props,
                                                      const float* __restrict__ scores) {
    const int b = blockIdx.x;
    const int tid = threadIdx.x;
    __shared__ unsigned int K0[KSZ], K1[KSZ];
    __shared__ unsigned short P0[KSZ], P1[KSZ];
    __shared__ unsigned short Hs[16 * HP];
    __shared__ unsigned int sWT[4];
    __shared__ int s_cnt;
    if (tid == 0) s_cnt = 0;
    __syncthreads();

    int localc = 0;
    for (int n = tid; n < NPAD; n += SORT_T) {
        unsigned int k = 0xFFFFFFu;
        if (n < NBOX) {
            const float2 sc = *reinterpret_cast<const float2*>(scores + ((size_t)b * NBOX + n) * 2);
            const float4 p  = *reinterpret_cast<const float4*>(props  + ((size_t)b * NBOX + n) * 4);
            const float fg = sc.y;
            const float w = __fsub_rn(p.z, p.x);
            const float h = __fsub_rn(p.w, p.y);
            if ((fg > 0.5f) && (w >= 16.0f) && (h >= 16.0f)) {
                k = 0x3F800000u - __float_as_uint(fg);
                localc++;
            }
        }
        K0[KIDX(n)] = k;
        P0[KIDX(n)] = (unsigned short)n;
    }
    for (int off = 32; off > 0; off >>= 1) localc += __shfl_down(localc, off);
    if ((tid & 63) == 0) atomicAdd(&s_cnt, localc);

    unsigned int kr[EPT];
    unsigned short pr[EPT];

    for (int pass = 0; pass < 6; ++pass) {
        const int shift = pass * 4;
        const unsigned int*   ksrc = (pass & 1) ? K1 : K0;
        unsigned int*         kdst = (pass & 1) ? K0 : K1;
        const unsigned short* psrc = (pass & 1) ? P1 : P0;
        unsigned short*       pdst = (pass & 1) ? P0 : P1;

        for (int hh = tid; hh < (16 * HP) / 2; hh += SORT_T)
            reinterpret_cast<unsigned int*>(Hs)[hh] = 0;
        __syncthreads();

        #pragma unroll
        for (int e = 0; e < EPT; ++e) {
            kr[e] = ksrc[tid * 17 + e];
            pr[e] = psrc[tid * 17 + e];
        }
        #pragma unroll
        for (int e = 0; e < EPT; ++e) {
            const unsigned int d = (kr[e] >> shift) & 15u;
            Hs[d * HP + tid]++;
        }
        __syncthreads();

        {
            const int d  = tid >> 4;
            const int t0 = (tid & 15) * 16;
            unsigned short* row = &Hs[d * HP];
            unsigned int sum = 0;
            #pragma unroll
            for (int e = 0; e < 16; ++e) {
                const unsigned int v = row[t0 + e];
                row[t0 + e] = (unsigned short)sum;
                sum += v;
            }
            unsigned int x = sum;
            #pragma unroll
            for (int off = 1; off < 64; off <<= 1) {
                const unsigned int y = __shfl_up(x, off);
                if ((tid & 63) >= off) x += y;
            }
            const int wid = tid >> 6;
            if ((tid & 63) == 63) sWT[wid] = x;
            __syncthreads();
            unsigned int base = x - sum;
            for (int w = 0; w < wid; ++w) base += sWT[w];
            #pragma unroll
            for (int e = 0; e < 16; ++e) row[t0 + e] += (unsigned short)base;
        }
        __syncthreads();

        #pragma unroll
        for (int e = 0; e < EPT; ++e) {
            const unsigned int d = (kr[e] >> shift) & 15u;
            const unsigned int pos = Hs[d * HP + tid]++;
            kdst[KIDX(pos)] = kr[e];
            pdst[KIDX(pos)] = pr[e];
        }
        __syncthreads();
    }

    const int nv = s_cnt;
    if (tid == 0) g_nvalid[b] = nv;
    for (int p = tid; p < NPAD; p += SORT_T) {
        if (p < nv) {
            const int idx = P0[KIDX(p)];
            g_sorted[b][p] = *reinterpret_cast<const float4*>(props + ((size_t)b * NBOX + idx) * 4);
        }
    }
}

// ---------------------------------------------------------------------------
// Kernel 2: suppression bitmask rows (triangular) + diagonal-word tile write.
// (unchanged) After the ballot loop, lane c holds word c of row i; lane (i>>6)
// holds the block-diagonal word, stored densely into g_tile64.
// ---------------------------------------------------------------------------
__global__ __launch_bounds__(64) void iou_kernel() {
    const int b = blockIdx.y;
    const int i = blockIdx.x;
    const int nv = g_nvalid[b];
    if (i >= nv) return;
    const int lane = threadIdx.x;
    const int c0 = i >> 6;
    const int W = (nv + 63) >> 6;

    const float4 bi = g_sorted[b][i];
    const float areai = __fmul_rn(__fsub_rn(bi.z, bi.x), __fsub_rn(bi.w, bi.y));

    u64 myword = 0ull;
    for (int c = c0; c < W; ++c) {
        const int j = (c << 6) + lane;
        bool pred = false;
        if (j < nv && j > i) {
            const float4 bj = g_sorted[b][j];
            const float areaj = __fmul_rn(__fsub_rn(bj.z, bj.x), __fsub_rn(bj.w, bj.y));
            const float xi1 = fmaxf(bi.x, bj.x);
            const float yi1 = fmaxf(bi.y, bj.y);
            const float xi2 = fminf(bi.z, bj.z);
            const float yi2 = fminf(bi.w, bj.w);
            const float iw = fmaxf(__fsub_rn(xi2, xi1), 0.0f);
            const float ih = fmaxf(__fsub_rn(yi2, yi1), 0.0f);
            const float inter = __fmul_rn(iw, ih);
            const float uni = __fsub_rn(__fadd_rn(areai, areaj), inter);
            pred = (inter / uni) >= 0.5f;
        }
        const u64 wd = __ballot(pred);
        if (lane == c) myword = wd;
    }
    g_sup[b][i][lane] = myword;
    if (lane == c0) g_tile64[b][c0][i & 63] = myword;
}

// ---------------------------------------------------------------------------
// Kernel 3: greedy scan, one wave per batch. Register-staged LDS pipeline:
// per block k: (1) ds_write regs holding block k+1's 64 full rows (loaded one
// iteration ago — the compiler emits a COUNTED vmcnt for this reg dependency,
// so ~a full block body of latency hiding; this is why global_load_lds was
// wrong here: its LDS aliasing forces a conservative vmcnt(0) each block);
// (2) issue block k+2's 32 ulonglong2 loads into the same regs (SSA WAR-safe);
// (3) scalar greedy on SALU (2 readlanes/kept row, proven R4); (4) batched OR
// from LDS (lgkm-only drain, ~200 cy). Zero exposed global latency per block.
// ---------------------------------------------------------------------------
__device__ __forceinline__ int rdl(int v, int l) {
    return __builtin_amdgcn_readlane(v, l);
}
__device__ __forceinline__ unsigned int rdlu(unsigned int v, int l) {
    return (unsigned int)__builtin_amdgcn_readlane((int)v, l);
}

__global__ __launch_bounds__(64, 1) void nms_kernel(float* __restrict__ out) {
    const int b = blockIdx.x;
    const int lane = threadIdx.x;
    int nv = g_nvalid[b];
    if (nv > NBOX) nv = NBOX;
    float4* outv = reinterpret_cast<float4*>(out) + (size_t)b * MAXK;
    const u64* gsup = &g_sup[b][0][0];
    const ulonglong2* g2 = reinterpret_cast<const ulonglong2*>(gsup);

    __shared__ u64 S[2][64][64];       // double-buffered 64-row caches (64 KB)

    // zero-fill output up-front (off the critical chain)
    for (int s = lane; s < MAXK; s += 64)
        outv[s] = make_float4(0.0f, 0.0f, 0.0f, 0.0f);

    const int nblk = (nv + 63) >> 6;   // <= 63, so all staged rows < NPAD

    ulonglong2 st[32];                 // 128 VGPRs of staging (1 wave/block, fine)

    // prologue: load block 0 -> write S[0] -> issue block 1 loads
    #pragma unroll
    for (int c = 0; c < 32; ++c) st[c] = g2[c * 64 + lane];
    {
        ulonglong2* d = reinterpret_cast<ulonglong2*>(&S[0][0][0]);
        #pragma unroll
        for (int c = 0; c < 32; ++c) d[c * 64 + lane] = st[c];
    }
    {
        const ulonglong2* gb = g2 + 64 * (WPR / 2);   // rows 64..127 (< NPAD)
        #pragma unroll
        for (int c = 0; c < 32; ++c) st[c] = gb[c * 64 + lane];
    }

    u64 removed = 0ull;                // lane w holds removed word w
    int kept = 0;
    u64 m_cur = g_tile64[b][0][lane];  // block-diagonal word of row lane

    for (int blk = 0; blk < nblk && kept < MAXK; ++blk) {
        const int base = blk << 6;
        // prefetch next block's tile column (reg dep, counted wait, off-chain)
        const u64 m_nxt = g_tile64[b][blk + 1][lane];   // blk+1 <= 63, in-bounds

        // (1) write block blk+1's rows (regs from last iteration) into LDS
        if (blk + 1 < nblk) {
            ulonglong2* d = reinterpret_cast<ulonglong2*>(&S[(blk + 1) & 1][0][0]);
            #pragma unroll
            for (int c = 0; c < 32; ++c) d[c * 64 + lane] = st[c];
        }
        // (2) issue block blk+2's loads (rows (blk+2)*64 .. +63, < NPAD: blk+2 <= 63)
        {
            const ulonglong2* gb = g2 + (size_t)(blk + 2) * 64 * (WPR / 2);
            #pragma unroll
            for (int c = 0; c < 32; ++c) st[c] = gb[c * 64 + lane];
        }

        // incoming suppression word (scalar)
        const unsigned int wv_lo = rdlu((unsigned int)removed, blk);
        const unsigned int wv_hi = rdlu((unsigned int)(removed >> 32), blk);
        u64 aliveU = ~(((u64)wv_hi << 32) | wv_lo);
        const int rem = nv - base;
        if (rem < 64) aliveU &= ((1ull << rem) - 1ull);
        unsigned int alive_lo = (unsigned int)__builtin_amdgcn_readfirstlane((int)(unsigned int)aliveU);
        unsigned int alive_hi = (unsigned int)__builtin_amdgcn_readfirstlane((int)(unsigned int)(aliveU >> 32));
        const unsigned int mc_lo = (unsigned int)m_cur;
        const unsigned int mc_hi = (unsigned int)(m_cur >> 32);

        // (3) scalar greedy (R4-proven: 2 readlanes per kept row)
        int m = 0;
        int myIdx = 0;                  // lane t holds the t-th kept index
        const int cap = MAXK - kept;
        while ((alive_lo | alive_hi) != 0u && m < cap) {
            const int l = alive_lo ? __builtin_ctz(alive_lo) : 32 + __builtin_ctz(alive_hi);
            const unsigned int sl_lo = rdlu(mc_lo, l);
            const unsigned int sl_hi = rdlu(mc_hi, l);
            const u64 clr = (((u64)sl_hi << 32) | sl_lo) | (1ull << l);
            alive_lo &= ~(unsigned int)clr;
            alive_hi &= ~(unsigned int)(clr >> 32);
            if (lane == m) myIdx = base + l;
            ++m;
        }

        if (m > 0) {
            // (4) batched OR from the LDS copy of THIS block's rows
            if (kept + m < MAXK && blk + 1 < nblk) {
                u64 (&Sb)[64][64] = S[blk & 1];
                for (int t = 0; t < m; t += 16) {
#define LDV(j) u64 v##j; {                                                      \
                        int tt = t + j; if (tt >= m) tt = m - 1;                \
                        const int it = rdl(myIdx, tt) - base;                   \
                        v##j = Sb[it][lane];                                    }
                    LDV(0)  LDV(1)  LDV(2)  LDV(3)
                    LDV(4)  LDV(5)  LDV(6)  LDV(7)
                    LDV(8)  LDV(9)  LDV(10) LDV(11)
                    LDV(12) LDV(13) LDV(14) LDV(15)
#undef LDV
                    removed |= (((v0 | v1) | (v2 | v3)) | ((v4 | v5) | (v6 | v7))) |
                               (((v8 | v9) | (v10 | v11)) | ((v12 | v13) | (v14 | v15)));
                }
            }
            // emit this block's outputs (off-chain; m <= cap)
            if (lane < m) outv[kept + lane] = g_sorted[b][myIdx];
            kept += m;
        }
        m_cur = m_nxt;
    }
}

extern "C" void kernel_launch(void* const* d_in, const int* in_sizes, int n_in,
                              void* d_out, int out_size, void* d_ws, size_t ws_size,
                              hipStream_t stream) {
    const float* props  = (const float*)d_in[0];   // (8,4000,4) f32
    const float* scores = (const float*)d_in[1];   // (8,4000,2) f32
    float* out = (float*)d_out;                    // (8,300,4) f32

    sort_kernel<<<BATCH, SORT_T, 0, stream>>>(props, scores);
    iou_kernel<<<dim3(NBOX, BATCH), 64, 0, stream>>>();
    nms_kernel<<<BATCH, 64, 0, stream>>>(out);
}